// Round 5
// baseline (1157.008 us; speedup 1.0000x reference)
//
#include <hip/hip_runtime.h>
#include <hip/hip_bf16.h>
#include <cmath>

#define HID 150
#define NN 100000
#define NE 1600000
#define NL 5
#define G3 (3*HID)          // 450
#define KP 320              // padded K: [aggr 0..149 | bias row 150 | pad | h 160..309 | pad]
#define NP 640              // padded N: 4 sections x 160 (r, z, i_n, h_n)
#define KS 10               // k-steps of 32
#define BM 128              // rows per block
#define HSTEPS 20           // half-k-steps (ks x {sec01, sec23})
#define HS_BF (20*64*8)     // bf16 per half-step chunk = 10240 (20 KB)

// bucketed CSR build (LDS-binned two-phase counting sort)
#define NPBSH 9             // 512 nodes per bucket
#define NBK 196             // ceil(100000 / 512)
#define CAPL 64             // LDS slots per bucket per chunk (lambda ~21, +9.4 sigma)
#define CAPG 10240          // global bucket capacity (mean 8163, sigma ~90)
#define CHUNK 4096          // edges per bin_edges block
#define BPAD 16             // bcnt stride in ints (one counter per cache line)

typedef __hip_bfloat16 bf16;
using short8 = __attribute__((ext_vector_type(8))) short;
using f32x4  = __attribute__((ext_vector_type(4))) float;

static __device__ __forceinline__ unsigned short bf_bits(float v) {
    __hip_bfloat16 h = __float2bfloat16(v);
    return *reinterpret_cast<unsigned short*>(&h);
}

static __device__ __forceinline__ float blo(unsigned int p) {
    return __uint_as_float((p & 0xffffu) << 16);
}
static __device__ __forceinline__ float bhi(unsigned int p) {
    return __uint_as_float(p & 0xffff0000u);
}

static __device__ __forceinline__ void gld_lds16(const void* g, void* l) {
    __builtin_amdgcn_global_load_lds(
        (const __attribute__((address_space(1))) void*)g,
        (__attribute__((address_space(3))) void*)l, 16, 0, 0);
}

// ---------------- build W fragments (per layer, half-step-contiguous B-frag order) ----
// chunk layout: [l][ks][half][tl(20)][lane(64)][8], tl = s2*10 + fgroup
__global__ void build_wfrag(const float* __restrict__ W, const float* __restrict__ w_ih,
                            const float* __restrict__ w_hh, const float* __restrict__ b_ih,
                            const float* __restrict__ b_hh, bf16* __restrict__ wfrag) {
    int idx = blockIdx.x * 256 + threadIdx.x;
    if (idx >= NL * KP * NP) return;
    int j = idx % NP;
    int k = (idx / NP) % KP;
    int l = idx / (NP * KP);
    int sec = j / 160;
    int f = j - sec * 160;
    float v = 0.f;
    if (f < HID) {
        if (k < HID) {
            if (sec < 3) {  // aggr rows: fused = W_l @ w_ih^T
                const float* Wl = W + (size_t)l * HID * HID + (size_t)k * HID;
                const float* wr = w_ih + (size_t)(sec * HID + f) * HID;
                float acc = 0.f;
                for (int t = 0; t < HID; ++t) acc += Wl[t] * wr[t];
                v = acc;
            }
        } else if (k == HID) {  // bias row (A has ones here)
            v = (sec == 0) ? b_ih[f] + b_hh[f]
              : (sec == 1) ? b_ih[HID + f] + b_hh[HID + f]
              : (sec == 2) ? b_ih[2 * HID + f]
                           : b_hh[2 * HID + f];
        } else if (k >= 160 && k < 160 + HID) {  // h rows
            int kk = k - 160;
            if (sec == 0)      v = w_hh[(size_t)f * HID + kk];
            else if (sec == 1) v = w_hh[(size_t)(HID + f) * HID + kk];
            else if (sec == 3) v = w_hh[(size_t)(2 * HID + f) * HID + kk];
        }
    }
    int kstep = k >> 5, kq = (k >> 3) & 3, ki = k & 7;
    int half = sec >> 1, s2 = sec & 1;
    int fgroup = f >> 4, nl = j & 15;
    int tl = s2 * 10 + fgroup;
    int lane = kq * 16 + nl;
    size_t addr = ((((size_t)(l * KS + kstep) * 2 + half) * 20 + tl) * 64 + lane) * 8 + ki;
    wfrag[addr] = __float2bfloat16(v);
}

// ---------------- CSR build phase A: LDS-binned edge bucketing ----------------
// pack: src in bits [16:0] (NN < 2^17), dst&511 in bits [25:17]
__global__ __launch_bounds__(256)
void bin_edges(const int* __restrict__ ei, int* __restrict__ bcnt,
               unsigned int* __restrict__ bbuf) {
    __shared__ int lcnt[NBK];
    __shared__ unsigned int lstage[NBK * CAPL];
    int t = threadIdx.x;
    for (int i = t; i < NBK; i += 256) lcnt[i] = 0;
    __syncthreads();
    int e0 = blockIdx.x * CHUNK;
#pragma unroll
    for (int it = 0; it < CHUNK / 256; ++it) {
        int e = e0 + it * 256 + t;
        if (e < NE) {
            int src = ei[e], dst = ei[NE + e];
            int b = dst >> NPBSH;
            unsigned int v = (unsigned int)src | ((unsigned int)(dst & 511) << 17);
            int li = atomicAdd(&lcnt[b], 1);
            if (li < CAPL) {
                lstage[b * CAPL + li] = v;
            } else {  // rare fallback (>9 sigma): direct global append, still correct
                int gp = atomicAdd(&bcnt[b * BPAD], 1);
                if (gp < CAPG) bbuf[(size_t)b * CAPG + gp] = v;
            }
        }
    }
    __syncthreads();
    // wave-cooperative flush: contiguous chunk per bucket -> full-line writes
    int wave = t >> 6, lane = t & 63;
    for (int b = wave; b < NBK; b += 4) {
        int cnt = lcnt[b];
        if (cnt > CAPL) cnt = CAPL;
        if (cnt == 0) continue;
        int base = 0;
        if (lane == 0) base = atomicAdd(&bcnt[b * BPAD], cnt);
        base = __shfl(base, 0, 64);
        if (lane < cnt && base + lane < CAPG)
            bbuf[(size_t)b * CAPG + base + lane] = lstage[b * CAPL + lane];
    }
}

// ---------------- CSR build phase B: per-bucket histogram + scan + scatter ------
// One block per bucket; produces off[] (replacing the old degree/scan pipeline)
// and csr[] via an L2-resident contiguous-window scatter.
__global__ __launch_bounds__(256)
void csr_from_buckets(const int* __restrict__ bcnt, const unsigned int* __restrict__ bbuf,
                      int* __restrict__ off, int* __restrict__ csr) {
    __shared__ int hist[512];
    __shared__ int s[256];
    int b = blockIdx.x, t = threadIdx.x;
    hist[t] = 0;
    hist[256 + t] = 0;
    // global base = sum of previous bucket counts (uniform scalar loop, tiny)
    int base = 0;
    for (int i = 0; i < b; ++i) {
        int c = bcnt[i * BPAD];
        base += (c > CAPG) ? CAPG : c;
    }
    int cnt = bcnt[b * BPAD];
    if (cnt > CAPG) cnt = CAPG;
    __syncthreads();
    // pass 1: per-node histogram in LDS
    for (int i = t; i < cnt; i += 256) {
        unsigned int v = bbuf[(size_t)b * CAPG + i];
        atomicAdd(&hist[v >> 17], 1);
    }
    __syncthreads();
    // exclusive scan of 512 counters (2 per thread + Hillis-Steele over 256)
    int a0 = hist[2 * t], a1 = hist[2 * t + 1];
    int tsum = a0 + a1;
    s[t] = tsum;
    __syncthreads();
    for (int d = 1; d < 256; d <<= 1) {
        int u = (t >= d) ? s[t - d] : 0;
        __syncthreads();
        s[t] += u;
        __syncthreads();
    }
    int tb = base + s[t] - tsum;
    hist[2 * t] = tb;
    hist[2 * t + 1] = tb + a0;
    int node = (b << NPBSH) + 2 * t;
    if (node < NN) off[node] = tb;
    if (node + 1 < NN) off[node + 1] = tb + a0;
    if (b == NBK - 1 && t == 255) off[NN] = base + s[255];
    __syncthreads();
    // pass 2: scatter into contiguous ~32 KB csr window (L2-resident)
    for (int i = t; i < cnt; i += 256) {
        unsigned int v = bbuf[(size_t)b * CAPG + i];
        int p = atomicAdd(&hist[v >> 17], 1);
        csr[p] = (int)(v & 0x1FFFFu);
    }
}

// ---------------- x -> Abuf h-region (bf16) ----------------
__global__ void init_h(const float* __restrict__ x, bf16* __restrict__ Abuf) {
    size_t i = (size_t)blockIdx.x * 256 + threadIdx.x;
    if (i >= (size_t)NN * HID) return;
    int m = (int)(i / HID), f = (int)(i - (size_t)m * HID);
    Abuf[(size_t)m * KP + 160 + f] = __float2bfloat16(x[i]);
}

// ---------------- aggregate: wave per node, 4-deep pipelined gather ----------------
__global__ void aggregate(bf16* __restrict__ Abuf, const int* __restrict__ off,
                          const int* __restrict__ csr) {
    int node = (blockIdx.x * blockDim.x + threadIdx.x) >> 6;
    int lane = threadIdx.x & 63;
    if (node >= NN) return;
    int e0 = off[node], e1 = off[node + 1];
    float a0 = 0.f, a1 = 0.f, b0 = 0.f, b1 = 0.f;
    bool tail = lane < 11;   // uints 64..74 cover features 128..149
    int e = e0;
    for (; e + 4 <= e1; e += 4) {
        const unsigned int* r0 = (const unsigned int*)(Abuf + (size_t)csr[e]     * KP + 160);
        const unsigned int* r1 = (const unsigned int*)(Abuf + (size_t)csr[e + 1] * KP + 160);
        const unsigned int* r2 = (const unsigned int*)(Abuf + (size_t)csr[e + 2] * KP + 160);
        const unsigned int* r3 = (const unsigned int*)(Abuf + (size_t)csr[e + 3] * KP + 160);
        unsigned int p0 = r0[lane], p1 = r1[lane], p2 = r2[lane], p3 = r3[lane];
        unsigned int q0 = 0, q1 = 0, q2 = 0, q3 = 0;
        if (tail) { q0 = r0[64 + lane]; q1 = r1[64 + lane]; q2 = r2[64 + lane]; q3 = r3[64 + lane]; }
        a0 += blo(p0) + blo(p1) + blo(p2) + blo(p3);
        a1 += bhi(p0) + bhi(p1) + bhi(p2) + bhi(p3);
        b0 += blo(q0) + blo(q1) + blo(q2) + blo(q3);
        b1 += bhi(q0) + bhi(q1) + bhi(q2) + bhi(q3);
    }
    for (; e < e1; ++e) {
        const unsigned int* r = (const unsigned int*)(Abuf + (size_t)csr[e] * KP + 160);
        unsigned int p = r[lane];
        unsigned int q = tail ? r[64 + lane] : 0;
        a0 += blo(p); a1 += bhi(p);
        b0 += blo(q); b1 += bhi(q);
    }
    unsigned int* out = (unsigned int*)(Abuf + (size_t)node * KP);
    out[lane] = (unsigned int)bf_bits(a0) | ((unsigned int)bf_bits(a1) << 16);
    if (tail) out[64 + lane] = (unsigned int)bf_bits(b0) | ((unsigned int)bf_bits(b1) << 16);
    if (lane < 5) out[75 + lane] = (lane == 0) ? 0x00003F80u : 0u;
}

// ---------------- fused GEMM + GRU epilogue, BM=128, 8 waves, paired staging ----
// 8 waves: mh = wave>>1 (32-row slab of 128), nh = wave&1 (feature half).
// B staged in half-step PAIRS (2560 x 16 B = exactly 5 loads x 512 threads),
// 3-pair-slot ring (6 x 20 KB). A: 3 x 8 KB ring (1 load/thread per k-step).
// Barrier + counted vmcnt only at EVEN half-steps (10 barriers); prefetch slack
// = 4 half-steps (~1500 cyc matrix work) >> L2 latency.
// Ring safety: pair p+2 / A(p+2) overwrite slots last read 2 barriers ago.
__global__ __launch_bounds__(512, 1)
void gemm_gru(const bf16* __restrict__ Abuf, const bf16* __restrict__ wfrag_l,
              float* __restrict__ h_out, bf16* __restrict__ Abuf_w, int last) {
    __shared__ __align__(16) bf16 Bs[6][HS_BF];       // 120 KB (3 pair slots)
    __shared__ __align__(16) bf16 As3[3][BM * 32];    // 24 KB
    int tid = threadIdx.x;
    int wave = tid >> 6, lane = tid & 63;
    int mh = wave >> 1, nh = wave & 1;
    int row0 = blockIdx.x * BM;

    const char* gbase = (const char*)(Abuf + (size_t)row0 * KP);

    auto stagePair = [&](int pp) {
        const char* gb = (const char*)(wfrag_l + (size_t)(pp * 2) * HS_BF);
        char* lb = (char*)Bs[(pp % 3) * 2];
#pragma unroll
        for (int it = 0; it < 5; ++it) {
            int c = it * 512 + tid;
            gld_lds16(gb + (size_t)c * 16, lb + (size_t)c * 16);
        }
    };
    auto stageA = [&](int ks) {
        gld_lds16(gbase + (size_t)(tid >> 2) * (KP * 2) + ks * 64 + (tid & 3) * 16,
                  (char*)As3[ks % 3] + (size_t)tid * 16);
    };

    // prologue: pair0(5) A0(1) pair1(5) A1(1) in flight (12 loads/thread)
    stagePair(0); stageA(0); stagePair(1); stageA(1);

    f32x4 acc[2][20];
#pragma unroll
    for (int mt = 0; mt < 2; ++mt)
#pragma unroll
        for (int t = 0; t < 20; ++t) acc[mt][t] = (f32x4){0.f, 0.f, 0.f, 0.f};

    int col = lane & 15, q = lane >> 4;
    short8 a0, a1;
#pragma unroll
    for (int hs = 0; hs < HSTEPS; ++hs) {
        int p2 = hs >> 1, half = hs & 1;
        if (half == 0) {
            // per-thread queue at this point: [pair(p2) x5, A(p2), pair(p2+1) x5, A(p2+1)]
            // wait for pair(p2)+A(p2) (oldest 6), leaving 6 younger in flight.
            if (hs < 18) asm volatile("s_waitcnt vmcnt(6)" ::: "memory");
            else         asm volatile("s_waitcnt vmcnt(0)" ::: "memory");
            __builtin_amdgcn_s_barrier();
            __builtin_amdgcn_sched_barrier(0);
            // overwrite slots last read at hs-2 (before previous barrier): safe
            if (p2 < 8) { stagePair(p2 + 2); stageA(p2 + 2); }
            const bf16* Ak = As3[p2 % 3];
            a0 = *(const short8*)(Ak + ((mh * 32 + col) * 32 + q * 8));
            a1 = *(const short8*)(Ak + ((mh * 32 + 16 + col) * 32 + q * 8));
        }
        const bf16* Bb = Bs[(p2 % 3) * 2 + half];
#pragma unroll
        for (int g = 0; g < 5; ++g) {
#pragma unroll
            for (int s2 = 0; s2 < 2; ++s2) {
                int tl = s2 * 10 + nh * 5 + g;
                short8 b = *(const short8*)(Bb + ((size_t)(tl * 64 + lane) * 8));
                int t = g * 4 + half * 2 + s2;
                acc[0][t] = __builtin_amdgcn_mfma_f32_16x16x32_bf16(a0, b, acc[0][t], 0, 0, 0);
                acc[1][t] = __builtin_amdgcn_mfma_f32_16x16x32_bf16(a1, b, acc[1][t], 0, 0, 0);
            }
        }
    }

    if (!last) __syncthreads();   // waves exit K-loop unsynced; Cs reuses Bs[0..1]

    // epilogue: C layout col=lane&15, row=(lane>>4)*4+reg ; hp re-read from global
    int qrow = q * 4;
    bf16* Cs = &Bs[0][0];   // reuse as [128][160] bf16 staging (40 KB)
#pragma unroll
    for (int mt = 0; mt < 2; ++mt) {
#pragma unroll
        for (int g = 0; g < 5; ++g) {
            int f = (nh * 5 + g) * 16 + col;
            if (f < HID) {
                f32x4 ar4 = acc[mt][g * 4 + 0], az = acc[mt][g * 4 + 1];
                f32x4 an = acc[mt][g * 4 + 2], ah = acc[mt][g * 4 + 3];
#pragma unroll
                for (int v = 0; v < 4; ++v) {
                    int rl = mh * 32 + mt * 16 + qrow + v;
                    float hp = __bfloat162float(Abuf[(size_t)(row0 + rl) * KP + 160 + f]);
                    float r = 1.f / (1.f + __expf(-ar4[v]));
                    float z = 1.f / (1.f + __expf(-az[v]));
                    float e2 = __expf(2.f * (an[v] + r * ah[v]));
                    float n = 1.f - 2.f / (e2 + 1.f);
                    float ho = (1.f - z) * n + z * hp;
                    if (last) {
                        int m = row0 + rl;
                        if (m < NN) h_out[(size_t)m * HID + f] = ho;
                    } else {
                        Cs[rl * 160 + f] = __float2bfloat16(ho);
                    }
                }
            }
        }
    }
    if (!last) {
        __syncthreads();
        // coalesced copy Cs -> Abuf h-region: 128 rows x 75 dwords (150 bf16)
        const unsigned int* src = (const unsigned int*)Cs;
        for (int i = tid; i < 128 * 75; i += 512) {
            int r2 = i / 75, dw = i - r2 * 75;
            ((unsigned int*)(Abuf_w + (size_t)(row0 + r2) * KP + 160))[dw] =
                src[r2 * 80 + dw];
        }
    }
}

extern "C" void kernel_launch(void* const* d_in, const int* in_sizes, int n_in,
                              void* d_out, int out_size, void* d_ws, size_t ws_size,
                              hipStream_t stream) {
    const float* x      = (const float*)d_in[0];
    const float* weight = (const float*)d_in[1];
    const float* w_ih   = (const float*)d_in[2];
    const float* w_hh   = (const float*)d_in[3];
    const float* b_ih   = (const float*)d_in[4];
    const float* b_hh   = (const float*)d_in[5];
    const int*   ei     = (const int*)d_in[6];
    float* h = (float*)d_out;

    const int nblk = (NN + BM - 1) / BM;          // 782
    const size_t NNP = (size_t)nblk * BM;
    char* p = (char*)d_ws;
    auto alloc = [&](size_t bytes) { char* r = p; p += (bytes + 255) & ~255ull; return r; };
    int*  off   = (int*)alloc((size_t)(NN + 1) * 4);
    int*  csr   = (int*)alloc((size_t)NE * 4);
    int*  bcnt  = (int*)alloc((size_t)NBK * BPAD * 4);
    unsigned int* bbuf = (unsigned int*)alloc((size_t)NBK * CAPG * 4);
    bf16* wfrag = (bf16*)alloc((size_t)NL * KS * 2 * HS_BF * 2);
    bf16* Abuf  = (bf16*)alloc((NNP + BM) * (size_t)KP * 2);

    hipMemsetAsync(bcnt, 0, (size_t)NBK * BPAD * 4, stream);
    build_wfrag<<<(NL * KP * NP + 255) / 256, 256, 0, stream>>>(weight, w_ih, w_hh, b_ih, b_hh, wfrag);
    bin_edges<<<(NE + CHUNK - 1) / CHUNK, 256, 0, stream>>>(ei, bcnt, bbuf);
    csr_from_buckets<<<NBK, 256, 0, stream>>>(bcnt, bbuf, off, csr);
    init_h<<<(int)(((size_t)NN * HID + 255) / 256), 256, 0, stream>>>(x, Abuf);

    for (int l = 0; l < NL; ++l) {
        aggregate<<<(NN * 64 + 255) / 256, 256, 0, stream>>>(Abuf, off, csr);
        gemm_gru<<<nblk, 512, 0, stream>>>(Abuf, wfrag + (size_t)l * KS * 2 * HS_BF,
                                           h, Abuf, (l == NL - 1) ? 1 : 0);
    }
}

// Round 6
// 1100.269 us; speedup vs baseline: 1.0516x; 1.0516x over previous
//
#include <hip/hip_runtime.h>
#include <hip/hip_bf16.h>
#include <cmath>

#define HID 150
#define NN 100000
#define NE 1600000
#define NL 5
#define G3 (3*HID)          // 450
#define KP 320              // padded K: [aggr 0..149 | bias row 150 | pad | h 160..309 | pad]
#define NP 640              // padded N: 4 sections x 160 (r, z, i_n, h_n)
#define KS 10               // k-steps of 32
#define BM 64               // rows per block
#define HSTEPS 20           // half-k-steps (ks x {sec01, sec23})
#define HS_BF (20*64*8)     // bf16 per half-step chunk = 10240 (20 KB)

// bucketed CSR build (LDS-binned two-phase counting sort)
#define NPBSH 9             // 512 nodes per bucket
#define NBK 196             // ceil(100000 / 512)
#define CAPL 64             // LDS slots per bucket per chunk (lambda ~21, +9.4 sigma)
#define CAPG 10240          // global bucket capacity (mean 8163, sigma ~90)
#define CHUNK 4096          // edges per bin_edges block
#define BPAD 16             // bcnt stride in ints (one counter per cache line)

typedef __hip_bfloat16 bf16;
using short8 = __attribute__((ext_vector_type(8))) short;
using f32x4  = __attribute__((ext_vector_type(4))) float;

static __device__ __forceinline__ unsigned short bf_bits(float v) {
    __hip_bfloat16 h = __float2bfloat16(v);
    return *reinterpret_cast<unsigned short*>(&h);
}

static __device__ __forceinline__ float blo(unsigned int p) {
    return __uint_as_float((p & 0xffffu) << 16);
}
static __device__ __forceinline__ float bhi(unsigned int p) {
    return __uint_as_float(p & 0xffff0000u);
}

static __device__ __forceinline__ void gld_lds16(const void* g, void* l) {
    __builtin_amdgcn_global_load_lds(
        (const __attribute__((address_space(1))) void*)g,
        (__attribute__((address_space(3))) void*)l, 16, 0, 0);
}

// ---------------- build W fragments (per layer, half-step-contiguous B-frag order) ----
// chunk layout: [l][ks][half][tl(20)][lane(64)][8], tl = s2*10 + fgroup
__global__ void build_wfrag(const float* __restrict__ W, const float* __restrict__ w_ih,
                            const float* __restrict__ w_hh, const float* __restrict__ b_ih,
                            const float* __restrict__ b_hh, bf16* __restrict__ wfrag) {
    int idx = blockIdx.x * 256 + threadIdx.x;
    if (idx >= NL * KP * NP) return;
    int j = idx % NP;
    int k = (idx / NP) % KP;
    int l = idx / (NP * KP);
    int sec = j / 160;
    int f = j - sec * 160;
    float v = 0.f;
    if (f < HID) {
        if (k < HID) {
            if (sec < 3) {  // aggr rows: fused = W_l @ w_ih^T
                const float* Wl = W + (size_t)l * HID * HID + (size_t)k * HID;
                const float* wr = w_ih + (size_t)(sec * HID + f) * HID;
                float acc = 0.f;
                for (int t = 0; t < HID; ++t) acc += Wl[t] * wr[t];
                v = acc;
            }
        } else if (k == HID) {  // bias row (A has ones here)
            v = (sec == 0) ? b_ih[f] + b_hh[f]
              : (sec == 1) ? b_ih[HID + f] + b_hh[HID + f]
              : (sec == 2) ? b_ih[2 * HID + f]
                           : b_hh[2 * HID + f];
        } else if (k >= 160 && k < 160 + HID) {  // h rows
            int kk = k - 160;
            if (sec == 0)      v = w_hh[(size_t)f * HID + kk];
            else if (sec == 1) v = w_hh[(size_t)(HID + f) * HID + kk];
            else if (sec == 3) v = w_hh[(size_t)(2 * HID + f) * HID + kk];
        }
    }
    int kstep = k >> 5, kq = (k >> 3) & 3, ki = k & 7;
    int half = sec >> 1, s2 = sec & 1;
    int fgroup = f >> 4, nl = j & 15;
    int tl = s2 * 10 + fgroup;
    int lane = kq * 16 + nl;
    size_t addr = ((((size_t)(l * KS + kstep) * 2 + half) * 20 + tl) * 64 + lane) * 8 + ki;
    wfrag[addr] = __float2bfloat16(v);
}

// ---------------- CSR build phase A: LDS-binned edge bucketing ----------------
// pack: src in bits [16:0] (NN < 2^17), dst&511 in bits [25:17]
__global__ __launch_bounds__(256)
void bin_edges(const int* __restrict__ ei, int* __restrict__ bcnt,
               unsigned int* __restrict__ bbuf) {
    __shared__ int lcnt[NBK];
    __shared__ unsigned int lstage[NBK * CAPL];
    int t = threadIdx.x;
    for (int i = t; i < NBK; i += 256) lcnt[i] = 0;
    __syncthreads();
    int e0 = blockIdx.x * CHUNK;
#pragma unroll
    for (int it = 0; it < CHUNK / 256; ++it) {
        int e = e0 + it * 256 + t;
        if (e < NE) {
            int src = ei[e], dst = ei[NE + e];
            int b = dst >> NPBSH;
            unsigned int v = (unsigned int)src | ((unsigned int)(dst & 511) << 17);
            int li = atomicAdd(&lcnt[b], 1);
            if (li < CAPL) {
                lstage[b * CAPL + li] = v;
            } else {  // rare fallback (>9 sigma): direct global append, still correct
                int gp = atomicAdd(&bcnt[b * BPAD], 1);
                if (gp < CAPG) bbuf[(size_t)b * CAPG + gp] = v;
            }
        }
    }
    __syncthreads();
    // wave-cooperative flush: contiguous chunk per bucket -> full-line writes
    int wave = t >> 6, lane = t & 63;
    for (int b = wave; b < NBK; b += 4) {
        int cnt = lcnt[b];
        if (cnt > CAPL) cnt = CAPL;
        if (cnt == 0) continue;
        int base = 0;
        if (lane == 0) base = atomicAdd(&bcnt[b * BPAD], cnt);
        base = __shfl(base, 0, 64);
        if (lane < cnt && base + lane < CAPG)
            bbuf[(size_t)b * CAPG + base + lane] = lstage[b * CAPL + lane];
    }
}

// ---------------- CSR build phase B: per-bucket histogram + scan + scatter ------
// One block per bucket; produces off[] (replacing the old degree/scan pipeline)
// and csr[] via an L2-resident contiguous-window scatter.
__global__ __launch_bounds__(256)
void csr_from_buckets(const int* __restrict__ bcnt, const unsigned int* __restrict__ bbuf,
                      int* __restrict__ off, int* __restrict__ csr) {
    __shared__ int hist[512];
    __shared__ int s[256];
    int b = blockIdx.x, t = threadIdx.x;
    hist[t] = 0;
    hist[256 + t] = 0;
    // global base = sum of previous bucket counts (uniform scalar loop, tiny)
    int base = 0;
    for (int i = 0; i < b; ++i) {
        int c = bcnt[i * BPAD];
        base += (c > CAPG) ? CAPG : c;
    }
    int cnt = bcnt[b * BPAD];
    if (cnt > CAPG) cnt = CAPG;
    __syncthreads();
    // pass 1: per-node histogram in LDS
    for (int i = t; i < cnt; i += 256) {
        unsigned int v = bbuf[(size_t)b * CAPG + i];
        atomicAdd(&hist[v >> 17], 1);
    }
    __syncthreads();
    // exclusive scan of 512 counters (2 per thread + Hillis-Steele over 256)
    int a0 = hist[2 * t], a1 = hist[2 * t + 1];
    int tsum = a0 + a1;
    s[t] = tsum;
    __syncthreads();
    for (int d = 1; d < 256; d <<= 1) {
        int u = (t >= d) ? s[t - d] : 0;
        __syncthreads();
        s[t] += u;
        __syncthreads();
    }
    int tb = base + s[t] - tsum;
    hist[2 * t] = tb;
    hist[2 * t + 1] = tb + a0;
    int node = (b << NPBSH) + 2 * t;
    if (node < NN) off[node] = tb;
    if (node + 1 < NN) off[node + 1] = tb + a0;
    if (b == NBK - 1 && t == 255) off[NN] = base + s[255];
    __syncthreads();
    // pass 2: scatter into contiguous ~32 KB csr window (L2-resident)
    for (int i = t; i < cnt; i += 256) {
        unsigned int v = bbuf[(size_t)b * CAPG + i];
        int p = atomicAdd(&hist[v >> 17], 1);
        csr[p] = (int)(v & 0x1FFFFu);
    }
}

// ---------------- x -> Abuf h-region (bf16) ----------------
__global__ void init_h(const float* __restrict__ x, bf16* __restrict__ Abuf) {
    size_t i = (size_t)blockIdx.x * 256 + threadIdx.x;
    if (i >= (size_t)NN * HID) return;
    int m = (int)(i / HID), f = (int)(i - (size_t)m * HID);
    Abuf[(size_t)m * KP + 160 + f] = __float2bfloat16(x[i]);
}

// ---------------- aggregate: wave per node, 8-deep pipelined gather ----------------
// 16 outstanding row-loads per wave (was 8): random-gather latency/queue hiding.
__global__ __launch_bounds__(256)
void aggregate(bf16* __restrict__ Abuf, const int* __restrict__ off,
               const int* __restrict__ csr) {
    int node = (blockIdx.x * blockDim.x + threadIdx.x) >> 6;
    int lane = threadIdx.x & 63;
    if (node >= NN) return;
    int e0 = off[node], e1 = off[node + 1];
    float a0 = 0.f, a1 = 0.f, b0 = 0.f, b1 = 0.f;
    bool tail = lane < 11;   // uints 64..74 cover features 128..149
    int e = e0;
    for (; e + 8 <= e1; e += 8) {
        const unsigned int* r0 = (const unsigned int*)(Abuf + (size_t)csr[e]     * KP + 160);
        const unsigned int* r1 = (const unsigned int*)(Abuf + (size_t)csr[e + 1] * KP + 160);
        const unsigned int* r2 = (const unsigned int*)(Abuf + (size_t)csr[e + 2] * KP + 160);
        const unsigned int* r3 = (const unsigned int*)(Abuf + (size_t)csr[e + 3] * KP + 160);
        const unsigned int* r4 = (const unsigned int*)(Abuf + (size_t)csr[e + 4] * KP + 160);
        const unsigned int* r5 = (const unsigned int*)(Abuf + (size_t)csr[e + 5] * KP + 160);
        const unsigned int* r6 = (const unsigned int*)(Abuf + (size_t)csr[e + 6] * KP + 160);
        const unsigned int* r7 = (const unsigned int*)(Abuf + (size_t)csr[e + 7] * KP + 160);
        unsigned int p0 = r0[lane], p1 = r1[lane], p2 = r2[lane], p3 = r3[lane];
        unsigned int p4 = r4[lane], p5 = r5[lane], p6 = r6[lane], p7 = r7[lane];
        unsigned int q0 = 0, q1 = 0, q2 = 0, q3 = 0, q4 = 0, q5 = 0, q6 = 0, q7 = 0;
        if (tail) {
            q0 = r0[64 + lane]; q1 = r1[64 + lane]; q2 = r2[64 + lane]; q3 = r3[64 + lane];
            q4 = r4[64 + lane]; q5 = r5[64 + lane]; q6 = r6[64 + lane]; q7 = r7[64 + lane];
        }
        a0 += blo(p0) + blo(p1) + blo(p2) + blo(p3) + blo(p4) + blo(p5) + blo(p6) + blo(p7);
        a1 += bhi(p0) + bhi(p1) + bhi(p2) + bhi(p3) + bhi(p4) + bhi(p5) + bhi(p6) + bhi(p7);
        b0 += blo(q0) + blo(q1) + blo(q2) + blo(q3) + blo(q4) + blo(q5) + blo(q6) + blo(q7);
        b1 += bhi(q0) + bhi(q1) + bhi(q2) + bhi(q3) + bhi(q4) + bhi(q5) + bhi(q6) + bhi(q7);
    }
    for (; e + 4 <= e1; e += 4) {
        const unsigned int* r0 = (const unsigned int*)(Abuf + (size_t)csr[e]     * KP + 160);
        const unsigned int* r1 = (const unsigned int*)(Abuf + (size_t)csr[e + 1] * KP + 160);
        const unsigned int* r2 = (const unsigned int*)(Abuf + (size_t)csr[e + 2] * KP + 160);
        const unsigned int* r3 = (const unsigned int*)(Abuf + (size_t)csr[e + 3] * KP + 160);
        unsigned int p0 = r0[lane], p1 = r1[lane], p2 = r2[lane], p3 = r3[lane];
        unsigned int q0 = 0, q1 = 0, q2 = 0, q3 = 0;
        if (tail) { q0 = r0[64 + lane]; q1 = r1[64 + lane]; q2 = r2[64 + lane]; q3 = r3[64 + lane]; }
        a0 += blo(p0) + blo(p1) + blo(p2) + blo(p3);
        a1 += bhi(p0) + bhi(p1) + bhi(p2) + bhi(p3);
        b0 += blo(q0) + blo(q1) + blo(q2) + blo(q3);
        b1 += bhi(q0) + bhi(q1) + bhi(q2) + bhi(q3);
    }
    for (; e < e1; ++e) {
        const unsigned int* r = (const unsigned int*)(Abuf + (size_t)csr[e] * KP + 160);
        unsigned int p = r[lane];
        unsigned int q = tail ? r[64 + lane] : 0;
        a0 += blo(p); a1 += bhi(p);
        b0 += blo(q); b1 += bhi(q);
    }
    unsigned int* out = (unsigned int*)(Abuf + (size_t)node * KP);
    out[lane] = (unsigned int)bf_bits(a0) | ((unsigned int)bf_bits(a1) << 16);
    if (tail) out[64 + lane] = (unsigned int)bf_bits(b0) | ((unsigned int)bf_bits(b1) << 16);
    if (lane < 5) out[75 + lane] = (lane == 0) ? 0x00003F80u : 0u;
}

// ---------------- fused GEMM + GRU epilogue, 3-deep pipelined staging ----------------
// (round-2 structure: BM=64, 4 waves, 2 blocks/CU — measured 94.5 us)
// Counted vmcnt + raw s_barrier: prefetches stay in flight across barriers.
// B: 3 x 20 KB ring (per half-step); A: 3 x 4 KB ring (per k-step, 64x32 bf16).
__global__ __launch_bounds__(256, 2)
void gemm_gru(const bf16* __restrict__ Abuf, const bf16* __restrict__ wfrag_l,
              float* __restrict__ h_out, bf16* __restrict__ Abuf_w, int last) {
    __shared__ __align__(16) bf16 Bs[3][HS_BF];       // 3 x 20 KB ring
    __shared__ __align__(16) bf16 As3[3][BM * 32];    // 3 x 4 KB ring
    int tid = threadIdx.x;
    int wave = tid >> 6, lane = tid & 63;
    int mh = wave >> 1, nh = wave & 1;
    int row0 = blockIdx.x * BM;

    const char* gbase = (const char*)(Abuf + (size_t)row0 * KP);
    int ar = tid >> 2, aq = tid & 3;

    auto stageB = [&](int hs) {
        const char* gb = (const char*)(wfrag_l + (size_t)hs * HS_BF);
        char* lb = (char*)Bs[hs % 3];
#pragma unroll
        for (int it = 0; it < 5; ++it) {
            int c = it * 256 + tid;
            gld_lds16(gb + (size_t)c * 16, lb + (size_t)c * 16);
        }
    };
    auto stageA = [&](int ks) {
        // 64 rows x 32 cols bf16 = 4 KB; thread t: row t>>2, 16B chunk t&3
        gld_lds16(gbase + (size_t)ar * (KP * 2) + ks * 64 + aq * 16,
                  (char*)As3[ks % 3] + (size_t)tid * 16);
    };

    // prologue: B0(5) A0(1) B1(5) A1(1) in flight (12 loads/thread)
    stageB(0); stageA(0); stageB(1); stageA(1);

    f32x4 acc[2][20];
#pragma unroll
    for (int mt = 0; mt < 2; ++mt)
#pragma unroll
        for (int t = 0; t < 20; ++t) acc[mt][t] = (f32x4){0.f, 0.f, 0.f, 0.f};

    int col = lane & 15, q = lane >> 4;
    short8 a0, a1;
#pragma unroll
    for (int hs = 0; hs < HSTEPS; ++hs) {
        // wait for B(hs) [and A(hs>>1)] to land, leaving younger prefetches in flight.
        // issue FIFO => in-order vmcnt retirement; younger-than-needed counts:
        // hs 0..17: next B stage (5) + next A stage (1) = 6; hs 18: 5; hs 19: 0.
        if (hs < 18)       asm volatile("s_waitcnt vmcnt(6)" ::: "memory");
        else if (hs == 18) asm volatile("s_waitcnt vmcnt(5)" ::: "memory");
        else               asm volatile("s_waitcnt vmcnt(0)" ::: "memory");
        __builtin_amdgcn_s_barrier();
        __builtin_amdgcn_sched_barrier(0);

        int ks = hs >> 1, half = hs & 1, cur = hs % 3;
        if (half == 0) {
            const bf16* Ak = As3[ks % 3];
            a0 = *(const short8*)(Ak + ((mh * 32 + col) * 32 + q * 8));
            a1 = *(const short8*)(Ak + ((mh * 32 + 16 + col) * 32 + q * 8));
        }
#pragma unroll
        for (int g = 0; g < 5; ++g) {
#pragma unroll
            for (int s2 = 0; s2 < 2; ++s2) {
                int tl = s2 * 10 + nh * 5 + g;
                short8 b = *(const short8*)(Bs[cur] + ((size_t)(tl * 64 + lane) * 8));
                int t = g * 4 + half * 2 + s2;
                acc[0][t] = __builtin_amdgcn_mfma_f32_16x16x32_bf16(a0, b, acc[0][t], 0, 0, 0);
                acc[1][t] = __builtin_amdgcn_mfma_f32_16x16x32_bf16(a1, b, acc[1][t], 0, 0, 0);
            }
        }
        // issue next stages (after this iteration's reads; before next barrier)
        if (hs + 2 < HSTEPS) stageB(hs + 2);
        if (half == 1 && ks + 2 < KS) stageA(ks + 2);
    }

    // epilogue: C layout col=lane&15, row=(lane>>4)*4+reg ; hp re-read from global
    int qrow = q * 4;
    bf16* Cs = &Bs[0][0];   // reuse as [64][160] bf16 staging for coalesced writes
#pragma unroll
    for (int mt = 0; mt < 2; ++mt) {
#pragma unroll
        for (int g = 0; g < 5; ++g) {
            int f = (nh * 5 + g) * 16 + col;
            if (f < HID) {
                f32x4 ar4 = acc[mt][g * 4 + 0], az = acc[mt][g * 4 + 1];
                f32x4 an = acc[mt][g * 4 + 2], ah = acc[mt][g * 4 + 3];
#pragma unroll
                for (int v = 0; v < 4; ++v) {
                    int rl = mh * 32 + mt * 16 + qrow + v;
                    float hp = __bfloat162float(Abuf[(size_t)(row0 + rl) * KP + 160 + f]);
                    float r = 1.f / (1.f + __expf(-ar4[v]));
                    float z = 1.f / (1.f + __expf(-az[v]));
                    float n = tanhf(an[v] + r * ah[v]);
                    float ho = (1.f - z) * n + z * hp;
                    if (last) {
                        int m = row0 + rl;
                        if (m < NN) h_out[(size_t)m * HID + f] = ho;
                    } else {
                        Cs[rl * 160 + f] = __float2bfloat16(ho);
                    }
                }
            }
        }
    }
    if (!last) {
        __syncthreads();
        // coalesced copy Cs -> Abuf h-region: 64 rows x 75 dwords (150 bf16)
        const unsigned int* src = (const unsigned int*)Cs;
        for (int i = tid; i < 64 * 75; i += 256) {
            int r = i / 75, dw = i - r * 75;
            ((unsigned int*)(Abuf_w + (size_t)(row0 + r) * KP + 160))[dw] =
                src[r * 80 + dw];
        }
    }
}

extern "C" void kernel_launch(void* const* d_in, const int* in_sizes, int n_in,
                              void* d_out, int out_size, void* d_ws, size_t ws_size,
                              hipStream_t stream) {
    const float* x      = (const float*)d_in[0];
    const float* weight = (const float*)d_in[1];
    const float* w_ih   = (const float*)d_in[2];
    const float* w_hh   = (const float*)d_in[3];
    const float* b_ih   = (const float*)d_in[4];
    const float* b_hh   = (const float*)d_in[5];
    const int*   ei     = (const int*)d_in[6];
    float* h = (float*)d_out;

    const int nblk = (NN + BM - 1) / BM;          // 1563
    const size_t NNP = (size_t)nblk * BM;
    char* p = (char*)d_ws;
    auto alloc = [&](size_t bytes) { char* r = p; p += (bytes + 255) & ~255ull; return r; };
    int*  off   = (int*)alloc((size_t)(NN + 1) * 4);
    int*  csr   = (int*)alloc((size_t)NE * 4);
    int*  bcnt  = (int*)alloc((size_t)NBK * BPAD * 4);
    unsigned int* bbuf = (unsigned int*)alloc((size_t)NBK * CAPG * 4);
    bf16* wfrag = (bf16*)alloc((size_t)NL * KS * 2 * HS_BF * 2);
    bf16* Abuf  = (bf16*)alloc((NNP + BM) * (size_t)KP * 2);

    hipMemsetAsync(bcnt, 0, (size_t)NBK * BPAD * 4, stream);
    build_wfrag<<<(NL * KP * NP + 255) / 256, 256, 0, stream>>>(weight, w_ih, w_hh, b_ih, b_hh, wfrag);
    bin_edges<<<(NE + CHUNK - 1) / CHUNK, 256, 0, stream>>>(ei, bcnt, bbuf);
    csr_from_buckets<<<NBK, 256, 0, stream>>>(bcnt, bbuf, off, csr);
    init_h<<<(int)(((size_t)NN * HID + 255) / 256), 256, 0, stream>>>(x, Abuf);

    for (int l = 0; l < NL; ++l) {
        aggregate<<<(NN * 64 + 255) / 256, 256, 0, stream>>>(Abuf, off, csr);
        gemm_gru<<<nblk, 256, 0, stream>>>(Abuf, wfrag + (size_t)l * KS * 2 * HS_BF,
                                           h, Abuf, (l == NL - 1) ? 1 : 0);
    }
}